// Round 1
// baseline (178.549 us; speedup 1.0000x reference)
//
#include <hip/hip_runtime.h>
#include <hip/hip_bf16.h>

// Embedding gather: out[t, :] = weight[ids[t], :]
// B*S = 8192 tokens, D = 1024 fp32 per row (4 KiB).
// One block per token; 256 threads x float4 = 1024 floats = one row.

#define D_DIM 1024

__global__ __launch_bounds__(256) void embed_gather_kernel(
    const int* __restrict__ ids,
    const float* __restrict__ weight,
    float* __restrict__ out,
    int n_tokens)
{
    const int t = blockIdx.x;
    if (t >= n_tokens) return;

    const int row = ids[t];  // lane-uniform -> scalar load + broadcast

    const float4* __restrict__ src =
        reinterpret_cast<const float4*>(weight + (size_t)row * D_DIM);
    float4* __restrict__ dst =
        reinterpret_cast<float4*>(out + (size_t)t * D_DIM);

    // D_DIM/4 = 256 float4 per row, 256 threads: one float4 each.
    dst[threadIdx.x] = src[threadIdx.x];
}

extern "C" void kernel_launch(void* const* d_in, const int* in_sizes, int n_in,
                              void* d_out, int out_size, void* d_ws, size_t ws_size,
                              hipStream_t stream) {
    const int*   ids    = (const int*)d_in[0];     // token_ids [B,S] int32
    const float* weight = (const float*)d_in[1];   // [VOCAB, D] fp32
    float*       out    = (float*)d_out;           // [B,S,D] fp32

    const int n_tokens = in_sizes[0];              // B*S = 8192

    embed_gather_kernel<<<n_tokens, 256, 0, stream>>>(ids, weight, out, n_tokens);
}